// Round 5
// baseline (3777.345 us; speedup 1.0000x reference)
//
#include <hip/hip_runtime.h>
#include <hip/hip_bf16.h>
#include <cstdint>

// ChromaticResonance R5: arch-VGPR live-range reduction (scheduling only;
// numerics bitwise-identical to R4, absmax 0.01855).
// R4 still spilled ~2GB: compiler splits unified file 128 arch + 128 AGPR;
// arch-side live set (ah/al 32 + B 24 + news 32 + oacc 32 + addr ~16) > 128.
// Fix: pipeline A-fragments per 16-row m-tile (live A 32->16) and pin with
// sched_barrier(0) so the scheduler can't hoist all tiles' loads back up.
// hi planes: [o:4][t:32][ks:16][lane:64][8]  o=0:C+H1, 1:H2, 2:H3, 3:H5
// lo planes (o0, H5 only): [p:2][t][ks][lane][8] at +HI_SZ.

typedef __bf16 bf16_t;
typedef bf16_t bf16x8 __attribute__((ext_vector_type(8)));
typedef float f32x4 __attribute__((ext_vector_type(4)));
typedef _Float16 h2_t __attribute__((ext_vector_type(2)));

#define B_ROWS 32768
#define D_DIM 512
#define N_DEPTH 7
#define MAT_SZ (32 * 16 * 64 * 8)   // 262144 u16 per packed matrix
#define HI_SZ (4 * MAT_SZ)          // 1048576 u16

__device__ __forceinline__ unsigned short f2b(float f) {
  bf16_t h = (bf16_t)f;
  return __builtin_bit_cast(unsigned short, h);
}
__device__ __forceinline__ float b2f(unsigned short u) {
  bf16_t h = __builtin_bit_cast(bf16_t, u);
  return (float)h;
}
__device__ __forceinline__ float fast_tanh(float x) {
  float ax = fabsf(x);
  float e = __expf(2.0f * ax);
  float t = 1.0f - 2.0f / (e + 1.0f);
  return copysignf(t, x);
}

// B-fragment map (mfma_f32_16x16x32_bf16): col = lane&15, k = (lane>>4)*8+i.
__global__ __launch_bounds__(256) void prepack_kernel(
    const float* __restrict__ cm, const float* __restrict__ h1,
    const float* __restrict__ h2, const float* __restrict__ h3,
    const float* __restrict__ h5, unsigned short* __restrict__ dst) {
  int gid = blockIdx.x * 256 + threadIdx.x;
  if (gid >= 4 * 32 * 16 * 64) return;
  int l  = gid & 63;
  int ks = (gid >> 6) & 15;
  int t  = (gid >> 10) & 31;
  int o  = gid >> 15;
  int n  = t * 16 + (l & 15);
  int k0 = ks * 32 + (l >> 4) * 8;
  unsigned short* ph = dst + (size_t)gid * 8;
  int lop = (o == 0) ? 0 : (o == 3) ? 1 : -1;
  unsigned short* pl = (lop >= 0)
      ? dst + HI_SZ + (size_t)lop * MAT_SZ + (size_t)(gid & 32767) * 8
      : nullptr;
#pragma unroll
  for (int i = 0; i < 8; ++i) {
    size_t idx = (size_t)(k0 + i) * D_DIM + n;
    float v = (o == 0) ? (cm[idx] + h1[idx])
            : (o == 1) ? h2[idx]
            : (o == 2) ? h3[idx]
                       : h5[idx];
    unsigned short h = f2b(v);
    ph[i] = h;
    if (pl) pl[i] = f2b(v - b2f(h));
  }
}

// LDS plane layout: [64 rows][512 bf16], 1KB/row, XOR swizzle.
__device__ __forceinline__ int lds_addr(int row, int byte_in_row) {
  return row * 1024 + (byte_in_row ^ ((row & 7) << 4));
}

__global__
__attribute__((amdgpu_flat_work_group_size(512, 512), amdgpu_waves_per_eu(2, 2)))
void resonance_kernel(
    const float* __restrict__ wr, const float* __restrict__ wi,
    const float* __restrict__ scale, const float* __restrict__ bias,
    const unsigned short* __restrict__ pre, float* __restrict__ out) {
  __shared__ unsigned short lds_hi[64 * 512];  // 64KB
  __shared__ unsigned short lds_lo[64 * 512];  // 64KB

  const int tid  = threadIdx.x;
  const int lane = tid & 63;
  const int wave = tid >> 6;  // 0..7
  const int ln15 = lane & 15;
  const int lg   = lane >> 4;  // 0..3
  const int r0   = blockIdx.x * 32;

  // ---- stage initial wave into hi/lo planes ----
#pragma unroll
  for (int it = 0; it < 8; ++it) {
    int idx = it * 512 + tid;
    int row = idx >> 6;
    int k0  = (idx & 63) * 8;
    const float* src = (row < 32) ? (wr + (size_t)(r0 + row) * D_DIM + k0)
                                  : (wi + (size_t)(r0 + row - 32) * D_DIM + k0);
    float4 v0 = *(const float4*)(src);
    float4 v1 = *(const float4*)(src + 4);
    float v[8] = {v0.x, v0.y, v0.z, v0.w, v1.x, v1.y, v1.z, v1.w};
    bf16x8 ph, pl;
#pragma unroll
    for (int j = 0; j < 8; ++j) {
      unsigned short h = f2b(v[j]);
      ph[j] = __builtin_bit_cast(bf16_t, h);
      pl[j] = (bf16_t)(v[j] - b2f(h));
    }
    int ad = lds_addr(row, k0 * 2);
    *(bf16x8*)((char*)lds_hi + ad) = ph;
    *(bf16x8*)((char*)lds_lo + ad) = pl;
  }
  __syncthreads();

  float Wsum = 0.0f;
#pragma unroll
  for (int d = 0; d < N_DEPTH; ++d) Wsum += __expf(-(float)d * (1.0f / 3.0f));
  const float invW = 1.0f / Wsum;

  h2_t oacc[4][2][4];  // packed fp16 (re, im) output accumulator
  h2_t news[4][2][4];  // packed fp16 chamber state for interference
#pragma unroll
  for (int c = 0; c < 4; ++c)
#pragma unroll
    for (int m = 0; m < 2; ++m)
#pragma unroll
      for (int r = 0; r < 4; ++r) oacc[c][m][r] = (h2_t){(_Float16)0.f, (_Float16)0.f};

  for (int depth = 0; depth < N_DEPTH; ++depth) {
    const float wd = __expf(-(float)depth * (1.0f / 3.0f)) * invW;

#pragma unroll
    for (int c = 0; c < 4; ++c) {
      const int t = c * 8 + wave;
      f32x4 acc0[4], acc1[4], acc2[4], acc3[4];
#pragma unroll
      for (int mt = 0; mt < 4; ++mt) {
        acc0[mt] = (f32x4){0.f, 0.f, 0.f, 0.f};
        acc1[mt] = (f32x4){0.f, 0.f, 0.f, 0.f};
        acc2[mt] = (f32x4){0.f, 0.f, 0.f, 0.f};
        acc3[mt] = (f32x4){0.f, 0.f, 0.f, 0.f};
      }

      const unsigned short* bcol = pre + (size_t)(t * 16) * 512 + lane * 8;
#pragma unroll 1
      for (int ks = 0; ks < 16; ++ks) {
        const unsigned short* bb = bcol + (size_t)ks * 512;
        bf16x8 b0h = *(const bf16x8*)(bb);
        bf16x8 b1h = *(const bf16x8*)(bb + 1 * MAT_SZ);
        bf16x8 b2h = *(const bf16x8*)(bb + 2 * MAT_SZ);
        bf16x8 b3h = *(const bf16x8*)(bb + 3 * MAT_SZ);
        bf16x8 b0l = *(const bf16x8*)(bb + HI_SZ);
        bf16x8 b3l = *(const bf16x8*)(bb + HI_SZ + MAT_SZ);

        const int kb = ks * 64 + lg * 16;
        bf16x8 ah, al;
        {
          int ad = lds_addr(ln15, kb);
          ah = *(const bf16x8*)((const char*)lds_hi + ad);
          al = *(const bf16x8*)((const char*)lds_lo + ad);
        }
#pragma unroll
        for (int mt = 0; mt < 4; ++mt) {
          bf16x8 nah, nal;
          if (mt < 3) {
            int ad = lds_addr((mt + 1) * 16 + ln15, kb);
            nah = *(const bf16x8*)((const char*)lds_hi + ad);
            nal = *(const bf16x8*)((const char*)lds_lo + ad);
          }
          acc0[mt] = __builtin_amdgcn_mfma_f32_16x16x32_bf16(ah, b0h, acc0[mt], 0, 0, 0);
          acc0[mt] = __builtin_amdgcn_mfma_f32_16x16x32_bf16(al, b0h, acc0[mt], 0, 0, 0);
          acc0[mt] = __builtin_amdgcn_mfma_f32_16x16x32_bf16(ah, b0l, acc0[mt], 0, 0, 0);
          acc1[mt] = __builtin_amdgcn_mfma_f32_16x16x32_bf16(ah, b1h, acc1[mt], 0, 0, 0);
          acc2[mt] = __builtin_amdgcn_mfma_f32_16x16x32_bf16(ah, b2h, acc2[mt], 0, 0, 0);
          acc3[mt] = __builtin_amdgcn_mfma_f32_16x16x32_bf16(ah, b3h, acc3[mt], 0, 0, 0);
          acc3[mt] = __builtin_amdgcn_mfma_f32_16x16x32_bf16(al, b3h, acc3[mt], 0, 0, 0);
          acc3[mt] = __builtin_amdgcn_mfma_f32_16x16x32_bf16(ah, b3l, acc3[mt], 0, 0, 0);
          __builtin_amdgcn_sched_barrier(0);
          if (mt < 3) { ah = nah; al = nal; }
        }
      }

      // ---- elementwise: rows mt*16+lg*4+r, col t*16+ln15 ----
      const int col = t * 16 + ln15;
      const float sclv = scale[col];
      const float biav = bias[col];
      const float damp = 0.1f / (1.0f + __expf(3.0f * (float)col * (1.0f / 511.0f)));
      const float fac  = __expf(-damp * (float)depth);
#pragma unroll
      for (int mt = 0; mt < 2; ++mt) {
#pragma unroll
        for (int r = 0; r < 4; ++r) {
          float lr = acc0[mt][r],  li = acc0[mt + 2][r];  // coupling + h1
          float re2 = acc1[mt][r], im2 = acc1[mt + 2][r];
          float ar = 0.25f * (re2 * re2 + im2 * im2);      // h2 real
          float re3 = acc2[mt][r], im3 = acc2[mt + 2][r];
          float m3 = re3 * re3 + im3 * im3;
          ar += 0.111111111f * m3 * re3;                   // h3
          float ai = 0.111111111f * m3 * im3;
          float re5 = acc3[mt][r], im5 = acc3[mt + 2][r];
          float m5 = re5 * re5 + im5 * im5;
          {
            // h5 = |hw|^(1/5) exp(i 5 ang) / 25
            float m5c = fmaxf(m5, 1e-36f);
            float inv = rsqrtf(m5c);
            float ur = re5 * inv, ui = im5 * inv;
            float u2r = ur * ur - ui * ui,     u2i = 2.0f * ur * ui;
            float u4r = u2r * u2r - u2i * u2i, u4i = 2.0f * u2r * u2i;
            float u5r = u4r * ur - u4i * ui,   u5i = u4r * ui + u4i * ur;
            float mag = __expf(0.1f * __logf(m5c));
            float msk = (m5 > 1e-36f) ? 0.04f : 0.0f;
            ar += msk * mag * u5r;
            ai += msk * mag * u5i;
          }
          float ir = lr + ar, ii = li + ai;
          if (depth > 0) {
            ir += (float)news[c][mt][r][0];
            ii += (float)news[c][mt][r][1];
          }
          float cre = fast_tanh(ir * sclv + biav) * fac;
          float cim = fast_tanh(ii * sclv + biav) * fac;
          oacc[c][mt][r] += (h2_t){(_Float16)(wd * cre), (_Float16)(wd * cim)};
          news[c][mt][r] = (h2_t){(_Float16)cre, (_Float16)cim};
        }
      }
    }

    if (depth < N_DEPTH - 1) {
      __syncthreads();  // all LDS reads of old state complete
#pragma unroll
      for (int c = 0; c < 4; ++c) {
        const int colb = ((c * 8 + wave) * 16 + ln15) * 2;
#pragma unroll
        for (int mt = 0; mt < 2; ++mt) {
#pragma unroll
          for (int r = 0; r < 4; ++r) {
            const int brow = mt * 16 + lg * 4 + r;
            float cre = (float)news[c][mt][r][0];
            float cim = (float)news[c][mt][r][1];
            unsigned short hr = f2b(cre);
            unsigned short lr = f2b(cre - b2f(hr));
            unsigned short hi = f2b(cim);
            unsigned short li = f2b(cim - b2f(hi));
            int ar_ = lds_addr(brow, colb);
            int ai_ = lds_addr(brow + 32, colb);
            *(unsigned short*)((char*)lds_hi + ar_) = hr;
            *(unsigned short*)((char*)lds_lo + ar_) = lr;
            *(unsigned short*)((char*)lds_hi + ai_) = hi;
            *(unsigned short*)((char*)lds_lo + ai_) = li;
          }
        }
      }
      __syncthreads();  // new state visible
    }
  }

  // ---- write weighted sum ----
#pragma unroll
  for (int c = 0; c < 4; ++c) {
    const int col = (c * 8 + wave) * 16 + ln15;
#pragma unroll
    for (int mt = 0; mt < 2; ++mt) {
#pragma unroll
      for (int r = 0; r < 4; ++r) {
        int brow = mt * 16 + lg * 4 + r;
        size_t base = (size_t)(r0 + brow) * D_DIM + col;
        out[base] = (float)oacc[c][mt][r][0];
        out[(size_t)B_ROWS * D_DIM + base] = (float)oacc[c][mt][r][1];
      }
    }
  }
}

extern "C" void kernel_launch(void* const* d_in, const int* in_sizes, int n_in,
                              void* d_out, int out_size, void* d_ws, size_t ws_size,
                              hipStream_t stream) {
  const float* wr = (const float*)d_in[0];
  const float* wi = (const float*)d_in[1];
  const float* cm = (const float*)d_in[2];
  const float* h1 = (const float*)d_in[3];
  const float* h2 = (const float*)d_in[4];
  const float* h3 = (const float*)d_in[5];
  const float* h5 = (const float*)d_in[6];
  const float* sc = (const float*)d_in[7];
  const float* bi = (const float*)d_in[8];
  unsigned short* pre = (unsigned short*)d_ws;  // 3.1MB packed B planes
  float* out = (float*)d_out;

  hipLaunchKernelGGL(prepack_kernel, dim3(512), dim3(256), 0, stream,
                     cm, h1, h2, h3, h5, pre);
  hipLaunchKernelGGL(resonance_kernel, dim3(B_ROWS / 32), dim3(512), 0, stream,
                     wr, wi, sc, bi, pre, out);
}

// Round 6
// 2088.051 us; speedup vs baseline: 1.8090x; 1.8090x over previous
//
#include <hip/hip_runtime.h>
#include <hip/hip_bf16.h>
#include <cstdint>

// ChromaticResonance R6: geometry change to kill spills + raise occupancy.
// R2-R5 invariant: VGPR=128 granted, ~210 demanded -> ~4GB scratch traffic,
// occupancy 24% (LDS-capped 1 block/CU). Fix: 16 complex rows/block
// (32 GEMM rows, 2 m-tiles). Persistent news+oacc: 64->32 VGPRs, acc 64->32,
// LDS 128->64KB -> 2 blocks/CU = 4 waves/SIMD. Numerics identical to R4.
// hi planes: [o:4][t:32][ks:16][lane:64][8]  o=0:C+H1, 1:H2, 2:H3, 3:H5
// lo planes (o0, H5 only): [p:2][t][ks][lane][8] at +HI_SZ.

typedef __bf16 bf16_t;
typedef bf16_t bf16x8 __attribute__((ext_vector_type(8)));
typedef float f32x4 __attribute__((ext_vector_type(4)));
typedef _Float16 h2_t __attribute__((ext_vector_type(2)));

#define B_ROWS 32768
#define D_DIM 512
#define N_DEPTH 7
#define CROWS 16                    // complex rows per block
#define MAT_SZ (32 * 16 * 64 * 8)   // 262144 u16 per packed matrix
#define HI_SZ (4 * MAT_SZ)          // 1048576 u16

__device__ __forceinline__ unsigned short f2b(float f) {
  bf16_t h = (bf16_t)f;
  return __builtin_bit_cast(unsigned short, h);
}
__device__ __forceinline__ float b2f(unsigned short u) {
  bf16_t h = __builtin_bit_cast(bf16_t, u);
  return (float)h;
}
__device__ __forceinline__ float fast_tanh(float x) {
  float ax = fabsf(x);
  float e = __expf(2.0f * ax);
  float t = 1.0f - 2.0f / (e + 1.0f);
  return copysignf(t, x);
}

// B-fragment map (mfma_f32_16x16x32_bf16): col = lane&15, k = (lane>>4)*8+i.
__global__ __launch_bounds__(256) void prepack_kernel(
    const float* __restrict__ cm, const float* __restrict__ h1,
    const float* __restrict__ h2, const float* __restrict__ h3,
    const float* __restrict__ h5, unsigned short* __restrict__ dst) {
  int gid = blockIdx.x * 256 + threadIdx.x;
  if (gid >= 4 * 32 * 16 * 64) return;
  int l  = gid & 63;
  int ks = (gid >> 6) & 15;
  int t  = (gid >> 10) & 31;
  int o  = gid >> 15;
  int n  = t * 16 + (l & 15);
  int k0 = ks * 32 + (l >> 4) * 8;
  unsigned short* ph = dst + (size_t)gid * 8;
  int lop = (o == 0) ? 0 : (o == 3) ? 1 : -1;
  unsigned short* pl = (lop >= 0)
      ? dst + HI_SZ + (size_t)lop * MAT_SZ + (size_t)(gid & 32767) * 8
      : nullptr;
#pragma unroll
  for (int i = 0; i < 8; ++i) {
    size_t idx = (size_t)(k0 + i) * D_DIM + n;
    float v = (o == 0) ? (cm[idx] + h1[idx])
            : (o == 1) ? h2[idx]
            : (o == 2) ? h3[idx]
                       : h5[idx];
    unsigned short h = f2b(v);
    ph[i] = h;
    if (pl) pl[i] = f2b(v - b2f(h));
  }
}

// LDS plane layout: [32 rows][512 bf16], 1KB/row, XOR swizzle.
__device__ __forceinline__ int lds_addr(int row, int byte_in_row) {
  return row * 1024 + (byte_in_row ^ ((row & 7) << 4));
}

__global__ __launch_bounds__(512) void resonance_kernel(
    const float* __restrict__ wr, const float* __restrict__ wi,
    const float* __restrict__ scale, const float* __restrict__ bias,
    const unsigned short* __restrict__ pre, float* __restrict__ out) {
  __shared__ unsigned short lds_hi[32 * 512];  // 32KB
  __shared__ unsigned short lds_lo[32 * 512];  // 32KB

  const int tid  = threadIdx.x;
  const int lane = tid & 63;
  const int wave = tid >> 6;  // 0..7
  const int ln15 = lane & 15;
  const int lg   = lane >> 4;  // 0..3
  const int r0   = blockIdx.x * CROWS;

  // ---- stage initial wave into hi/lo planes ----
  // GEMM rows: 0-15 = re(complex rows 0-15), 16-31 = im.
#pragma unroll
  for (int it = 0; it < 4; ++it) {
    int idx = it * 512 + tid;  // 0..2047, 8 elements each
    int row = idx >> 6;        // 0..31
    int k0  = (idx & 63) * 8;
    const float* src = (row < CROWS)
        ? (wr + (size_t)(r0 + row) * D_DIM + k0)
        : (wi + (size_t)(r0 + row - CROWS) * D_DIM + k0);
    float4 v0 = *(const float4*)(src);
    float4 v1 = *(const float4*)(src + 4);
    float v[8] = {v0.x, v0.y, v0.z, v0.w, v1.x, v1.y, v1.z, v1.w};
    bf16x8 ph, pl;
#pragma unroll
    for (int j = 0; j < 8; ++j) {
      unsigned short h = f2b(v[j]);
      ph[j] = __builtin_bit_cast(bf16_t, h);
      pl[j] = (bf16_t)(v[j] - b2f(h));
    }
    int ad = lds_addr(row, k0 * 2);
    *(bf16x8*)((char*)lds_hi + ad) = ph;
    *(bf16x8*)((char*)lds_lo + ad) = pl;
  }
  __syncthreads();

  float Wsum = 0.0f;
#pragma unroll
  for (int d = 0; d < N_DEPTH; ++d) Wsum += __expf(-(float)d * (1.0f / 3.0f));
  const float invW = 1.0f / Wsum;

  h2_t oacc[4][4];  // [chunk][r] packed fp16 (re, im) output accumulator
  h2_t news[4][4];  // [chunk][r] packed fp16 chamber state for interference
#pragma unroll
  for (int c = 0; c < 4; ++c)
#pragma unroll
    for (int r = 0; r < 4; ++r) oacc[c][r] = (h2_t){(_Float16)0.f, (_Float16)0.f};

  for (int depth = 0; depth < N_DEPTH; ++depth) {
    const float wd = __expf(-(float)depth * (1.0f / 3.0f)) * invW;

#pragma unroll
    for (int c = 0; c < 4; ++c) {
      const int t = c * 8 + wave;
      f32x4 acc0[2], acc1[2], acc2[2], acc3[2];
#pragma unroll
      for (int mt = 0; mt < 2; ++mt) {
        acc0[mt] = (f32x4){0.f, 0.f, 0.f, 0.f};
        acc1[mt] = (f32x4){0.f, 0.f, 0.f, 0.f};
        acc2[mt] = (f32x4){0.f, 0.f, 0.f, 0.f};
        acc3[mt] = (f32x4){0.f, 0.f, 0.f, 0.f};
      }

#pragma unroll 2
      for (int ks = 0; ks < 16; ++ks) {
        bf16x8 ah[2], al[2];
#pragma unroll
        for (int mt = 0; mt < 2; ++mt) {
          int ad = lds_addr(mt * 16 + ln15, ks * 64 + lg * 16);
          ah[mt] = *(const bf16x8*)((const char*)lds_hi + ad);
          al[mt] = *(const bf16x8*)((const char*)lds_lo + ad);
        }
        const unsigned short* bb = pre + (size_t)(t * 16 + ks) * 512 + lane * 8;
        bf16x8 b0h = *(const bf16x8*)(bb);
        bf16x8 b1h = *(const bf16x8*)(bb + 1 * MAT_SZ);
        bf16x8 b2h = *(const bf16x8*)(bb + 2 * MAT_SZ);
        bf16x8 b3h = *(const bf16x8*)(bb + 3 * MAT_SZ);
        bf16x8 b0l = *(const bf16x8*)(bb + HI_SZ);
        bf16x8 b3l = *(const bf16x8*)(bb + HI_SZ + MAT_SZ);
#pragma unroll
        for (int mt = 0; mt < 2; ++mt) {
          acc0[mt] = __builtin_amdgcn_mfma_f32_16x16x32_bf16(ah[mt], b0h, acc0[mt], 0, 0, 0);
          acc0[mt] = __builtin_amdgcn_mfma_f32_16x16x32_bf16(al[mt], b0h, acc0[mt], 0, 0, 0);
          acc0[mt] = __builtin_amdgcn_mfma_f32_16x16x32_bf16(ah[mt], b0l, acc0[mt], 0, 0, 0);
          acc1[mt] = __builtin_amdgcn_mfma_f32_16x16x32_bf16(ah[mt], b1h, acc1[mt], 0, 0, 0);
          acc2[mt] = __builtin_amdgcn_mfma_f32_16x16x32_bf16(ah[mt], b2h, acc2[mt], 0, 0, 0);
          acc3[mt] = __builtin_amdgcn_mfma_f32_16x16x32_bf16(ah[mt], b3h, acc3[mt], 0, 0, 0);
          acc3[mt] = __builtin_amdgcn_mfma_f32_16x16x32_bf16(al[mt], b3h, acc3[mt], 0, 0, 0);
          acc3[mt] = __builtin_amdgcn_mfma_f32_16x16x32_bf16(ah[mt], b3l, acc3[mt], 0, 0, 0);
        }
      }

      // ---- elementwise: complex rows lg*4+r, col t*16+ln15 ----
      const int col = t * 16 + ln15;
      const float sclv = scale[col];
      const float biav = bias[col];
      const float damp = 0.1f / (1.0f + __expf(3.0f * (float)col * (1.0f / 511.0f)));
      const float fac  = __expf(-damp * (float)depth);
#pragma unroll
      for (int r = 0; r < 4; ++r) {
        float lr = acc0[0][r],  li = acc0[1][r];   // coupling + h1
        float re2 = acc1[0][r], im2 = acc1[1][r];
        float ar = 0.25f * (re2 * re2 + im2 * im2);  // h2 real
        float re3 = acc2[0][r], im3 = acc2[1][r];
        float m3 = re3 * re3 + im3 * im3;
        ar += 0.111111111f * m3 * re3;               // h3
        float ai = 0.111111111f * m3 * im3;
        float re5 = acc3[0][r], im5 = acc3[1][r];
        float m5 = re5 * re5 + im5 * im5;
        {
          // h5 = |hw|^(1/5) exp(i 5 ang) / 25
          float m5c = fmaxf(m5, 1e-36f);
          float inv = rsqrtf(m5c);
          float ur = re5 * inv, ui = im5 * inv;
          float u2r = ur * ur - ui * ui,     u2i = 2.0f * ur * ui;
          float u4r = u2r * u2r - u2i * u2i, u4i = 2.0f * u2r * u2i;
          float u5r = u4r * ur - u4i * ui,   u5i = u4r * ui + u4i * ur;
          float mag = __expf(0.1f * __logf(m5c));
          float msk = (m5 > 1e-36f) ? 0.04f : 0.0f;
          ar += msk * mag * u5r;
          ai += msk * mag * u5i;
        }
        float ir = lr + ar, ii = li + ai;
        if (depth > 0) {
          ir += (float)news[c][r][0];
          ii += (float)news[c][r][1];
        }
        float cre = fast_tanh(ir * sclv + biav) * fac;
        float cim = fast_tanh(ii * sclv + biav) * fac;
        oacc[c][r] += (h2_t){(_Float16)(wd * cre), (_Float16)(wd * cim)};
        news[c][r] = (h2_t){(_Float16)cre, (_Float16)cim};
      }
    }

    if (depth < N_DEPTH - 1) {
      __syncthreads();  // all LDS reads of old state complete
#pragma unroll
      for (int c = 0; c < 4; ++c) {
        const int colb = ((c * 8 + wave) * 16 + ln15) * 2;
#pragma unroll
        for (int r = 0; r < 4; ++r) {
          const int brow = lg * 4 + r;  // complex row 0..15
          float cre = (float)news[c][r][0];
          float cim = (float)news[c][r][1];
          unsigned short hr = f2b(cre);
          unsigned short lr = f2b(cre - b2f(hr));
          unsigned short hi = f2b(cim);
          unsigned short li = f2b(cim - b2f(hi));
          int ar_ = lds_addr(brow, colb);
          int ai_ = lds_addr(brow + CROWS, colb);
          *(unsigned short*)((char*)lds_hi + ar_) = hr;
          *(unsigned short*)((char*)lds_lo + ar_) = lr;
          *(unsigned short*)((char*)lds_hi + ai_) = hi;
          *(unsigned short*)((char*)lds_lo + ai_) = li;
        }
      }
      __syncthreads();  // new state visible
    }
  }

  // ---- write weighted sum ----
#pragma unroll
  for (int c = 0; c < 4; ++c) {
    const int col = (c * 8 + wave) * 16 + ln15;
#pragma unroll
    for (int r = 0; r < 4; ++r) {
      int brow = lg * 4 + r;
      size_t base = (size_t)(r0 + brow) * D_DIM + col;
      out[base] = (float)oacc[c][r][0];
      out[(size_t)B_ROWS * D_DIM + base] = (float)oacc[c][r][1];
    }
  }
}

extern "C" void kernel_launch(void* const* d_in, const int* in_sizes, int n_in,
                              void* d_out, int out_size, void* d_ws, size_t ws_size,
                              hipStream_t stream) {
  const float* wr = (const float*)d_in[0];
  const float* wi = (const float*)d_in[1];
  const float* cm = (const float*)d_in[2];
  const float* h1 = (const float*)d_in[3];
  const float* h2 = (const float*)d_in[4];
  const float* h3 = (const float*)d_in[5];
  const float* h5 = (const float*)d_in[6];
  const float* sc = (const float*)d_in[7];
  const float* bi = (const float*)d_in[8];
  unsigned short* pre = (unsigned short*)d_ws;  // 3.1MB packed B planes
  float* out = (float*)d_out;

  hipLaunchKernelGGL(prepack_kernel, dim3(512), dim3(256), 0, stream,
                     cm, h1, h2, h3, h5, pre);
  hipLaunchKernelGGL(resonance_kernel, dim3(B_ROWS / CROWS), dim3(512), 0, stream,
                     wr, wi, sc, bi, pre, out);
}